// Round 1
// baseline (144.238 us; speedup 1.0000x reference)
//
#include <hip/hip_runtime.h>
#include <math.h>

#define BSZ 512
#define DD 2048
#define KK 128
#define PP 5
#define NCOL (KK * PP)   // 640
#define OUTW (DD + KK)   // 2176

// ---------------------------------------------------------------------------
// Kernel 1: column sums of theta^2  ->  norm[col] (atomic accumulate)
// 40960 threads: col = i % 640 (coalesced across lanes), seg = i / 640,
// each thread sums 32 rows.
// ---------------------------------------------------------------------------
__global__ __launch_bounds__(256) void norm_kernel(const float* __restrict__ theta,
                                                   float* __restrict__ norm) {
    int i   = blockIdx.x * 256 + threadIdx.x;   // 0..40959
    int col = i % NCOL;
    int seg = i / NCOL;                         // 0..63
    const float* p = theta + (size_t)seg * 32 * NCOL + col;
    float s = 0.f;
#pragma unroll
    for (int j = 0; j < 32; ++j) {
        float v = p[(size_t)j * NCOL];
        s += v * v;
    }
    atomicAdd(&norm[col], s);
}

// ---------------------------------------------------------------------------
// Kernel 2: raw GEMM  actv[b, col] = sum_d x[b,d] * theta[d,col]
// fp32 vector ALU (no fp32 MFMA on CDNA4). 64x64 tiles, split-K=4,
// atomicAdd epilogue into zero-initialized actv.
// ---------------------------------------------------------------------------
#define BM 64
#define BN 64
#define BK 16
#define KSPLIT 4
#define KCHUNK (DD / KSPLIT)   // 512

__global__ __launch_bounds__(256) void gemm_kernel(const float* __restrict__ x,
                                                   const float* __restrict__ theta,
                                                   float* __restrict__ actv) {
    __shared__ float As[BK][BM];   // k-major (transposed A tile)
    __shared__ float Bs[BK][BN];

    const int t  = threadIdx.x;
    const int tx = t & 15;         // 0..15 -> n micro
    const int ty = t >> 4;         // 0..15 -> m micro
    const int m0 = blockIdx.y * BM;
    const int n0 = blockIdx.x * BN;
    const int kz = blockIdx.z * KCHUNK;

    // staging indices
    const int ar = t >> 2;          // 0..63  row of A tile
    const int ac = (t & 3) * 4;     // 0,4,8,12 col group (4 floats)
    const int bk = t >> 4;          // 0..15  row of B tile
    const int bn = (t & 15) * 4;    // col group

    float acc[4][4] = {};

    for (int kb = kz; kb < kz + KCHUNK; kb += BK) {
        const float4 av = *(const float4*)&x[(size_t)(m0 + ar) * DD + kb + ac];
        const float4 bv = *(const float4*)&theta[(size_t)(kb + bk) * NCOL + n0 + bn];
        __syncthreads();   // previous iteration's reads done
        As[ac + 0][ar] = av.x;
        As[ac + 1][ar] = av.y;
        As[ac + 2][ar] = av.z;
        As[ac + 3][ar] = av.w;
        *(float4*)&Bs[bk][bn] = bv;
        __syncthreads();
#pragma unroll
        for (int kk = 0; kk < BK; ++kk) {
            const float4 a = *(const float4*)&As[kk][ty * 4];
            const float4 b = *(const float4*)&Bs[kk][tx * 4];
            acc[0][0] += a.x * b.x; acc[0][1] += a.x * b.y; acc[0][2] += a.x * b.z; acc[0][3] += a.x * b.w;
            acc[1][0] += a.y * b.x; acc[1][1] += a.y * b.y; acc[1][2] += a.y * b.z; acc[1][3] += a.y * b.w;
            acc[2][0] += a.z * b.x; acc[2][1] += a.z * b.y; acc[2][2] += a.z * b.z; acc[2][3] += a.z * b.w;
            acc[3][0] += a.w * b.x; acc[3][1] += a.w * b.y; acc[3][2] += a.w * b.z; acc[3][3] += a.w * b.w;
        }
    }

#pragma unroll
    for (int i = 0; i < 4; ++i)
#pragma unroll
        for (int j = 0; j < 4; ++j)
            atomicAdd(&actv[(size_t)(m0 + ty * 4 + i) * NCOL + n0 + tx * 4 + j], acc[i][j]);
}

// ---------------------------------------------------------------------------
// Kernel 3: copy x into out[:, 0:D]  (float4)
// ---------------------------------------------------------------------------
__global__ __launch_bounds__(256) void copy_kernel(const float* __restrict__ x,
                                                   float* __restrict__ out) {
    int i = blockIdx.x * 256 + threadIdx.x;   // 0..262143 (512 rows * 512 f4)
    int r = i >> 9;
    int c = i & 511;
    float4 v = *(const float4*)&x[(size_t)r * DD + c * 4];
    *(float4*)&out[(size_t)r * OUTW + c * 4] = v;
}

// ---------------------------------------------------------------------------
// Kernel 4: per-k pairwise L1 -> exp -> rowsum.
// grid (k=128, half=2), block 256. Stage scaled actv_k [512][5] into LDS
// (stride 8 -> 16B-aligned rows, broadcast ds_read_b128 in inner loop).
// f[b,k] = sum_{b2} exp(-s) - 1 + bias[k]   (diag term is exactly 1)
// ---------------------------------------------------------------------------
__global__ __launch_bounds__(256) void pairwise_kernel(const float* __restrict__ actv,
                                                       const float* __restrict__ norm,
                                                       const float* __restrict__ lws,
                                                       const float* __restrict__ bias,
                                                       float* __restrict__ out) {
    const int k   = blockIdx.x;    // 0..127
    const int tid = threadIdx.x;

    __shared__ float sA[BSZ][8];   // 16 KiB, rows 32B-aligned
    __shared__ float sScale[PP];

    if (tid < PP) {
        const int col = k * PP + tid;
        const float e = __builtin_amdgcn_exp2f(lws[col] * 1.4426950408889634f);
        sScale[tid] = e * __builtin_amdgcn_rsqf(norm[col]);
    }
    __syncthreads();

    for (int i = tid; i < BSZ * PP; i += 256) {
        int b = i / PP;
        int p = i - b * PP;
        sA[b][p] = actv[(size_t)b * NCOL + k * PP + p] * sScale[p];
    }
    __syncthreads();

    const int b = blockIdx.y * 256 + tid;
    const float4 a03 = *(const float4*)&sA[b][0];
    const float  a4  = sA[b][4];

    const float c = -1.4426950408889634f;
    float acc = 0.f;
#pragma unroll 4
    for (int b2 = 0; b2 < BSZ; ++b2) {
        const float4 v  = *(const float4*)&sA[b2][0];
        const float  v4 = sA[b2][4];
        float s = fabsf(a03.x - v.x) + fabsf(a03.y - v.y) + fabsf(a03.z - v.z) +
                  fabsf(a03.w - v.w) + fabsf(a4 - v4);
        acc += __builtin_amdgcn_exp2f(c * s);
    }

    out[(size_t)b * OUTW + DD + k] = acc - 1.0f + bias[k];
}

// ---------------------------------------------------------------------------
extern "C" void kernel_launch(void* const* d_in, const int* in_sizes, int n_in,
                              void* d_out, int out_size, void* d_ws, size_t ws_size,
                              hipStream_t stream) {
    const float* x     = (const float*)d_in[0];   // [512, 2048]
    const float* theta = (const float*)d_in[1];   // [2048, 128, 5]
    const float* lws   = (const float*)d_in[2];   // [128, 5]
    const float* bias  = (const float*)d_in[3];   // [128]
    float* out = (float*)d_out;                   // [512, 2176]

    float* norm = (float*)d_ws;        // 640 floats
    float* actv = norm + NCOL;         // 512*640 floats

    // zero atomic-accumulate targets (ws is poisoned 0xAA each call)
    hipMemsetAsync(d_ws, 0, (size_t)(NCOL + BSZ * NCOL) * sizeof(float), stream);

    norm_kernel<<<160, 256, 0, stream>>>(theta, norm);
    gemm_kernel<<<dim3(NCOL / BN, BSZ / BM, KSPLIT), 256, 0, stream>>>(x, theta, actv);
    copy_kernel<<<(BSZ * DD / 4) / 256, 256, 0, stream>>>(x, out);
    pairwise_kernel<<<dim3(KK, 2), 256, 0, stream>>>(actv, norm, lws, bias, out);
}